// Round 6
// baseline (386.406 us; speedup 1.0000x reference)
//
#include <hip/hip_runtime.h>

#define DI __device__ __forceinline__

// ---------------- ws layout (float offsets) ----------------
// umax[8] (uint32) at 0: [0]=|x| [1]=|act0| [2]=|act1| [3]=|act2| [4]=|act3| [5]=|act4|
constexpr int OFF_WSF0 = 8;
constexpr int OFF_BNS0 = 40;
constexpr int OFF_BNB0 = 72;
constexpr int OFF_W0I  = 104;    // 32*27
constexpr int OFF_WSF1 = 968;
constexpr int OFF_BNS1 = 972;
constexpr int OFF_BNB1 = 976;
constexpr int OFF_W1I  = 980;    // 4*32
constexpr int OFF_WSF2 = 1108;
constexpr int OFF_BNS2 = 1140;
constexpr int OFF_BNB2 = 1172;
constexpr int OFF_W2I  = 1204;   // 32*36
constexpr int OFF_WSF3 = 2356;
constexpr int OFF_BNS3 = 2388;
constexpr int OFF_BNB3 = 2420;
constexpr int OFF_W3I  = 2452;   // 32*288
constexpr int OFF_WSF4 = 11668;
constexpr int OFF_BNS4 = 11700;
constexpr int OFF_BNB4 = 11732;
constexpr int OFF_W4I  = 11764;  // 9216
constexpr int OFF_WSFD = 20980;  // 10
constexpr int OFF_WDI  = 20992;  // 20480
constexpr int OFF_LOG  = 41472;  // 10240
constexpr int OFF_ACT  = 51712;
constexpr long ACT_A_OFF = OFF_ACT;              // act2/act4
constexpr long ACT_B_OFF = OFF_ACT + 8388608L;   // act1/act3

// ---------------- helpers ----------------
DI float quantv(float x, float sf) {
    float q = rintf(x / sf);
    return fminf(fmaxf(q, -127.0f), 127.0f);
}
DI float get_sf(const unsigned* umax, int slot) {
    return fmaxf(__uint_as_float(umax[slot]) / 127.0f, 1e-8f);
}
DI void block_max_atomic(float v, unsigned* dst) {
    __shared__ float redm_[4];
    #pragma unroll
    for (int o = 32; o; o >>= 1) v = fmaxf(v, __shfl_down(v, o, 64));
    int wid = threadIdx.x >> 6;
    if ((threadIdx.x & 63) == 0) redm_[wid] = v;
    __syncthreads();
    if (threadIdx.x == 0) {
        int nw = blockDim.x >> 6;
        float m = redm_[0];
        for (int i = 1; i < nw; ++i) m = fmaxf(m, redm_[i]);
        atomicMax(dst, __float_as_uint(m));
    }
}

// ---------------- prep: weight quant + BN fold ----------------
struct PrepEntry {
    const float *w, *g, *bb, *m, *v;
    float *wsf, *wint, *bns, *bnb;
    int K; int has_bn;
};
struct PrepAll { PrepEntry e[6]; unsigned* umax; };

__global__ __launch_bounds__(256) void k_prep_all(PrepAll pa) {
    int blk = blockIdx.x;
    if (blk == 142) { if (threadIdx.x < 8) pa.umax[threadIdx.x] = 0u; return; }
    int layer, oc;
    if      (blk < 32)  { layer = 0; oc = blk; }
    else if (blk < 36)  { layer = 1; oc = blk - 32; }
    else if (blk < 68)  { layer = 2; oc = blk - 36; }
    else if (blk < 100) { layer = 3; oc = blk - 68; }
    else if (blk < 132) { layer = 4; oc = blk - 100; }
    else                { layer = 5; oc = blk - 132; }
    PrepEntry a = pa.e[layer];
    const float* wr = a.w + (long)oc * a.K;
    float mx = 0.f;
    for (int i = threadIdx.x; i < a.K; i += 256) mx = fmaxf(mx, fabsf(wr[i]));
    __shared__ float red[4];
    __shared__ float s_sf;
    #pragma unroll
    for (int o = 32; o; o >>= 1) mx = fmaxf(mx, __shfl_down(mx, o, 64));
    if ((threadIdx.x & 63) == 0) red[threadIdx.x >> 6] = mx;
    __syncthreads();
    if (threadIdx.x == 0) {
        float t = fmaxf(fmaxf(red[0], red[1]), fmaxf(red[2], red[3]));
        t = fmaxf(t / 127.0f, 1e-8f);
        a.wsf[oc] = t; s_sf = t;
        if (a.has_bn) {
            float inv = a.g[oc] / sqrtf(a.v[oc] + 1e-5f);
            a.bns[oc] = inv;
            a.bnb[oc] = a.bb[oc] - a.m[oc] * inv;
        }
    }
    __syncthreads();
    float sf = s_sf;
    for (int i = threadIdx.x; i < a.K; i += 256) a.wint[(long)oc * a.K + i] = rintf(wr[i] / sf);
}

__global__ __launch_bounds__(256) void k_absmax(const float4* __restrict__ x, int n4, unsigned* dst) {
    float m = 0.f;
    for (int i = blockIdx.x * blockDim.x + threadIdx.x; i < n4; i += gridDim.x * blockDim.x) {
        float4 t = x[i];
        m = fmaxf(m, fmaxf(fmaxf(fabsf(t.x), fabsf(t.y)), fmaxf(fabsf(t.z), fabsf(t.w))));
    }
    block_max_atomic(m, dst);
}

// ---------------- conv0 band machinery ----------------
// block = (image, 8-row band). tile [3][10][36] = 1080; weights k-major [27][32] = 864.
// thread = 4 oc x 8 px: ocg = tid>>5 (8 groups), pxg = tid&31: row = pxg>>2, cb = (pxg&3)*8.
DI void conv0_band_stage(const float* xb, float sfx, int r0, float* tile,
                         const float* w0i, float* wlds, int tid) {
    for (int i = tid; i < 1080; i += 256) tile[i] = 0.f;
    for (int i = tid; i < 864; i += 256) {
        int k = i >> 5, oc = i & 31;
        wlds[i] = w0i[oc * 27 + k];
    }
    __syncthreads();
    for (int i = tid; i < 960; i += 256) {   // 3 ci * 10 rows * 32 cols
        int ci = i / 320, rem = i - ci * 320;
        int rr = rem >> 5, cc = rem & 31;
        int gr = r0 - 1 + rr;
        if ((unsigned)gr < 32u)
            tile[ci * 360 + rr * 36 + cc + 1] = quantv(xb[ci * 1024 + gr * 32 + cc], sfx);
    }
}

// inner accumulation: acc[4 oc][8 px], integer-exact (order-free)
DI void conv0_band_acc(const float* tile, const float* wlds, int ocg, int row, int cb,
                       float acc[4][8]) {
    #pragma unroll 1
    for (int ci = 0; ci < 3; ++ci) {
        #pragma unroll
        for (int ky = 0; ky < 3; ++ky) {
            const float* rp = tile + ci * 360 + (row + ky) * 36 + cb;
            float wn[12];
            #pragma unroll
            for (int d = 0; d < 3; ++d) *(float4*)&wn[4 * d] = *(const float4*)&rp[4 * d];
            #pragma unroll
            for (int kx = 0; kx < 3; ++kx) {
                float4 wv = *(const float4*)&wlds[((ci * 3 + ky) * 3 + kx) * 32 + ocg * 4];
                const float* wf = &wv.x;
                #pragma unroll
                for (int o = 0; o < 4; ++o)
                    #pragma unroll
                    for (int p = 0; p < 8; ++p)
                        acc[o][p] = fmaf(wn[p + kx], wf[o], acc[o][p]);
            }
        }
    }
}

// pass 1: conv0+BN max only. grid 4096 = (image, band)
__global__ __launch_bounds__(256) void k_conv0maxN(
    const float* __restrict__ x, const float* __restrict__ w0i,
    const float* __restrict__ wsf0, const float* __restrict__ bias0,
    const float* __restrict__ bns0, const float* __restrict__ bnb0,
    const unsigned* __restrict__ umax, unsigned* __restrict__ mout) {
    __shared__ float tile[1080];
    __shared__ float wlds[864];
    __shared__ float As[32], Cs[32];
    const int b  = blockIdx.x >> 2;
    const int r0 = (blockIdx.x & 3) * 8;
    const int tid = threadIdx.x;
    const float sfx = get_sf(umax, 0);
    if (tid < 32) {
        int oc = tid;
        float bsf = wsf0[oc] * sfx;
        float bint = rintf(bias0[oc] / bsf);
        float a = bsf * bns0[oc];
        As[oc] = a;
        Cs[oc] = fmaf(bint, a, bnb0[oc]);
    }
    conv0_band_stage(x + (long)b * 3072, sfx, r0, tile, w0i, wlds, tid);
    __syncthreads();
    const int ocg = tid >> 5;
    const int pxg = tid & 31;
    const int row = pxg >> 2;
    const int cb  = (pxg & 3) * 8;
    float acc[4][8] = {};
    conv0_band_acc(tile, wlds, ocg, row, cb, acc);
    float lmax = 0.f;
    #pragma unroll
    for (int o = 0; o < 4; ++o) {
        float A = As[ocg * 4 + o], C = Cs[ocg * 4 + o];
        #pragma unroll
        for (int p = 0; p < 8; ++p)
            lmax = fmaxf(lmax, fabsf(fmaf(acc[o][p], A, C)));
    }
    block_max_atomic(lmax, mout);
}

// pass 2: conv0 recompute + quant + partial 1x1 conv1 + shfl/LDS reduce + BN1. grid 4096
__global__ __launch_bounds__(256) void k_conv01n(
    const float* __restrict__ x, const float* __restrict__ w0i,
    const float* __restrict__ wsf0, const float* __restrict__ bias0,
    const float* __restrict__ bns0, const float* __restrict__ bnb0,
    const float* __restrict__ w1i,
    const float* __restrict__ wsf1, const float* __restrict__ bias1,
    const float* __restrict__ bns1, const float* __restrict__ bnb1,
    const unsigned* __restrict__ umax, unsigned* __restrict__ mout,
    float* __restrict__ out) {
    __shared__ float tile[1080];
    __shared__ float wlds[864];
    __shared__ float w1s[128];
    __shared__ float As[32], Cs[32];
    __shared__ float A1s[4], C1s[4];
    __shared__ float red[4][32][36];   // [wave][pxg][o1*8+p] padded
    const int b  = blockIdx.x >> 2;
    const int r0 = (blockIdx.x & 3) * 8;
    const int tid = threadIdx.x;
    const float sfx = get_sf(umax, 0);
    const float sf1 = get_sf(umax, 1);
    if (tid < 32) {
        int oc = tid;
        float bsf = wsf0[oc] * sfx;
        float bint = rintf(bias0[oc] / bsf);
        float a = bsf * bns0[oc];
        As[oc] = a;
        Cs[oc] = fmaf(bint, a, bnb0[oc]);
    }
    if (tid >= 64 && tid < 68) {
        int oc = tid - 64;
        float bsf = wsf1[oc] * sf1;
        float bint = rintf(bias1[oc] / bsf);
        float a = bsf * bns1[oc];
        A1s[oc] = a;
        C1s[oc] = fmaf(bint, a, bnb1[oc]);
    }
    if (tid >= 128 && tid < 256) w1s[tid - 128] = w1i[tid - 128];
    conv0_band_stage(x + (long)b * 3072, sfx, r0, tile, w0i, wlds, tid);
    __syncthreads();
    const int ocg = tid >> 5;
    const int pxg = tid & 31;
    const int row = pxg >> 2;
    const int cb  = (pxg & 3) * 8;
    float acc[4][8] = {};
    conv0_band_acc(tile, wlds, ocg, row, cb, acc);
    // quantize act0 + partial 1x1 conv1 over this thread's 4 input channels
    float acc1[4][8] = {};
    #pragma unroll
    for (int o = 0; o < 4; ++o) {
        int oc = ocg * 4 + o;
        float A = As[oc], C = Cs[oc];
        float w1r0 = w1s[oc], w1r1 = w1s[32 + oc], w1r2 = w1s[64 + oc], w1r3 = w1s[96 + oc];
        #pragma unroll
        for (int p = 0; p < 8; ++p) {
            float q = quantv(fmaf(acc[o][p], A, C), sf1);
            acc1[0][p] = fmaf(q, w1r0, acc1[0][p]);
            acc1[1][p] = fmaf(q, w1r1, acc1[1][p]);
            acc1[2][p] = fmaf(q, w1r2, acc1[2][p]);
            acc1[3][p] = fmaf(q, w1r3, acc1[3][p]);
        }
    }
    // reduce over ocg: lane^32 within wave (integer-exact, order-free)
    #pragma unroll
    for (int o1 = 0; o1 < 4; ++o1)
        #pragma unroll
        for (int p = 0; p < 8; ++p)
            acc1[o1][p] += __shfl_xor(acc1[o1][p], 32, 64);
    const int wv = tid >> 6;
    if ((tid & 63) < 32) {
        float* rp = &red[wv][pxg][0];
        #pragma unroll
        for (int d = 0; d < 8; ++d)
            *(float4*)&rp[4 * d] = *(float4*)&acc1[d >> 1][(d & 1) * 4];
    }
    __syncthreads();
    // final: sum 4 waves, BN1, write. thread = (out row, col)
    const int col  = tid & 31;
    const int orow = tid >> 5;
    const int pxg2 = orow * 4 + (col >> 3);
    const int ps   = col & 7;
    float lmax = 0.f;
    float* ob = out + (long)b * 4096 + (r0 + orow) * 32 + col;
    #pragma unroll
    for (int o1 = 0; o1 < 4; ++o1) {
        int j = o1 * 8 + ps;
        float s = (red[0][pxg2][j] + red[1][pxg2][j]) + (red[2][pxg2][j] + red[3][pxg2][j]);
        float y = fmaf(s, A1s[o1], C1s[o1]);
        lmax = fmaxf(lmax, fabsf(y));
        ob[o1 * 1024] = y;
    }
    block_max_atomic(lmax, mout);
}

// ---------------- conv2 (4->32, 3x3, s2): thread = 8 oc x 4 px, weights k-major LDS ----------------
__global__ __launch_bounds__(256) void k_conv2c(
    const float* __restrict__ inp, const float* __restrict__ wgl,
    const float* __restrict__ wsf, const float* __restrict__ bias,
    const float* __restrict__ bns, const float* __restrict__ bnb,
    const unsigned* __restrict__ umax, unsigned* __restrict__ mout,
    float* __restrict__ out) {
    __shared__ float tile[4 * 34 * 36];   // 4896
    __shared__ float wlds[36 * 32];       // 1152, k-major
    __shared__ float As[32], Cs[32];
    const int tid = threadIdx.x;
    const float sf = get_sf(umax, 2);
    if (tid < 32) {
        int oc = tid;
        float bsf = wsf[oc] * sf;
        float bint = rintf(bias[oc] / bsf);
        float a = bsf * bns[oc];
        As[oc] = a;
        Cs[oc] = fmaf(bint, a, bnb[oc]);
    }
    for (int i = tid; i < 4896; i += 256) tile[i] = 0.f;
    for (int i = tid; i < 1152; i += 256) {
        int k = i >> 5, oc = i & 31;
        wlds[i] = wgl[oc * 36 + k];
    }
    __syncthreads();
    const float* ib = inp + (long)blockIdx.x * 4096;
    for (int i = tid; i < 4096; i += 256) {
        int ci = i >> 10, px = i & 1023;
        int iy = px >> 5, ix = px & 31;
        tile[ci * 1224 + (iy + 1) * 36 + (ix + 1)] = quantv(ib[i], sf);
    }
    __syncthreads();
    const int oc0 = (tid >> 6) * 8;
    const int pxq = tid & 63;
    const int h = pxq >> 2, c = pxq & 3;
    float acc[8][4];
    #pragma unroll
    for (int k = 0; k < 8; ++k)
        #pragma unroll
        for (int p = 0; p < 4; ++p) acc[k][p] = 0.f;
    #pragma unroll 1
    for (int ci = 0; ci < 4; ++ci) {
        #pragma unroll
        for (int ky = 0; ky < 3; ++ky) {
            const float* rp = tile + ci * 1224 + (2 * h + ky) * 36 + 8 * c;
            float wn[12];
            #pragma unroll
            for (int d = 0; d < 3; ++d) *(float4*)&wn[4 * d] = *(const float4*)&rp[4 * d];
            #pragma unroll
            for (int kx = 0; kx < 3; ++kx) {
                const float* wp = &wlds[(ci * 9 + ky * 3 + kx) * 32 + oc0];
                float4 wa = *(const float4*)&wp[0];
                float4 wb = *(const float4*)&wp[4];
                float wf[8] = {wa.x, wa.y, wa.z, wa.w, wb.x, wb.y, wb.z, wb.w};
                #pragma unroll
                for (int k = 0; k < 8; ++k)
                    #pragma unroll
                    for (int p = 0; p < 4; ++p)
                        acc[k][p] = fmaf(wn[2 * p + kx], wf[k], acc[k][p]);
            }
        }
    }
    float lmax = 0.f;
    float* ob = out + (long)blockIdx.x * 8192;
    #pragma unroll
    for (int k = 0; k < 8; ++k) {
        int oc = oc0 + k;
        float A = As[oc], C = Cs[oc];
        float4 r;
        float* rp = &r.x;
        #pragma unroll
        for (int p = 0; p < 4; ++p) {
            float y = fmaf(acc[k][p], A, C);
            rp[p] = y;
            lmax = fmaxf(lmax, fabsf(y));
        }
        *(float4*)&ob[oc * 256 + h * 16 + c * 4] = r;
    }
    block_max_atomic(lmax, mout);
}

// ---------------- conv3/conv4: 2 img/block, 4oc x 4px, K-phased LDS ----------------
template<int HIN, int S>
__global__ __launch_bounds__(256) void k_conv34b(
    const float* __restrict__ inp, const float* __restrict__ wi,
    const float* __restrict__ wsf, const float* __restrict__ bias,
    const float* __restrict__ bns, const float* __restrict__ bnb,
    const unsigned* __restrict__ umax, int slot, unsigned* __restrict__ mout,
    float* __restrict__ out) {
    constexpr int ROWS = HIN + 2;
    constexpr int RS   = (S == 2) ? 20 : 12;
    constexpr int TI   = 8 * ROWS * RS;
    constexpr int PIX  = HIN * HIN;
    constexpr int NELT = 2 * 8 * PIX;
    constexpr int WINW = (S == 2) ? 12 : 8;
    constexpr int ND   = (S == 2) ? 3 : 2;
    __shared__ float tile[2 * TI];
    __shared__ float wlds[72 * 36];
    __shared__ float As[32], Cs[32];
    const int tid  = threadIdx.x;
    const int imgl = tid >> 7;
    const int ocg  = (tid >> 4) & 7;
    const int pxq  = tid & 15;
    const int h = pxq >> 1, c = pxq & 1;
    const float sf = get_sf(umax, slot);
    if (tid < 32) {
        int oc = tid;
        float bsf = wsf[oc] * sf;
        float bint = rintf(bias[oc] / bsf);
        float a = bsf * bns[oc];
        As[oc] = a;
        Cs[oc] = fmaf(bint, a, bnb[oc]);
    }
    for (int i = tid; i < 2 * TI; i += 256) tile[i] = 0.f;
    float acc[16];
    #pragma unroll
    for (int i = 0; i < 16; ++i) acc[i] = 0.f;
    const float* ib = inp + (long)blockIdx.x * 2 * 32 * PIX;
    for (int ph = 0; ph < 4; ++ph) {
        __syncthreads();
        for (int i = tid; i < NELT; i += 256) {
            int im = i / (8 * PIX);
            int r  = i % (8 * PIX);
            int ci = r / PIX;
            int px = r % PIX;
            int iy = px / HIN, ix = px % HIN;
            tile[(im * 8 + ci) * (ROWS * RS) + (iy + 1) * RS + (ix + 1)] =
                quantv(ib[(long)(im * 32 + ph * 8 + ci) * PIX + px], sf);
        }
        for (int i = tid; i < 2304; i += 256) {
            int oc = i / 72, k = i - oc * 72;
            wlds[k * 36 + oc] = wi[oc * 288 + ph * 72 + k];
        }
        __syncthreads();
        const float* tb = tile + imgl * TI;
        #pragma unroll 2
        for (int ci = 0; ci < 8; ++ci) {
            float win[3][WINW];
            #pragma unroll
            for (int ky = 0; ky < 3; ++ky) {
                const float* rp = tb + ci * (ROWS * RS) + (S * h + ky) * RS + S * 4 * c;
                #pragma unroll
                for (int d = 0; d < ND; ++d)
                    *(float4*)&win[ky][4 * d] = *(const float4*)&rp[4 * d];
            }
            #pragma unroll
            for (int ky = 0; ky < 3; ++ky)
                #pragma unroll
                for (int kx = 0; kx < 3; ++kx) {
                    int j = ky * 3 + kx;
                    float4 wv = *(const float4*)&wlds[(ci * 9 + j) * 36 + ocg * 4];
                    float wvf[4] = {wv.x, wv.y, wv.z, wv.w};
                    #pragma unroll
                    for (int k = 0; k < 4; ++k)
                        #pragma unroll
                        for (int px = 0; px < 4; ++px)
                            acc[k * 4 + px] = fmaf(win[ky][S * px + kx], wvf[k], acc[k * 4 + px]);
                }
        }
    }
    float lmax = 0.f;
    long imgg = (long)blockIdx.x * 2 + imgl;
    #pragma unroll
    for (int k = 0; k < 4; ++k) {
        int oc = ocg * 4 + k;
        float A = As[oc], C = Cs[oc];
        float4 r;
        float* rp = &r.x;
        #pragma unroll
        for (int px = 0; px < 4; ++px) {
            float y = fmaf(acc[k * 4 + px], A, C);
            rp[px] = y;
            lmax = fmaxf(lmax, fabsf(y));
        }
        *(float4*)&out[(imgg * 32 + oc) * 64 + h * 8 + c * 4] = r;
    }
    block_max_atomic(lmax, mout);
}

// ---------------- linear 2048->10 per image ----------------
__global__ __launch_bounds__(256) void k_fc(
    const float* __restrict__ act, const float* __restrict__ wdi,
    const float* __restrict__ wsfd, const float* __restrict__ bd,
    const unsigned* __restrict__ umax, float* __restrict__ logits) {
    int b = blockIdx.x;
    float sf = get_sf(umax, 5);
    const float* ab = act + (long)b * 2048;
    float acc[10] = {0.f, 0.f, 0.f, 0.f, 0.f, 0.f, 0.f, 0.f, 0.f, 0.f};
    #pragma unroll
    for (int k = 0; k < 8; ++k) {
        int j = threadIdx.x + 256 * k;
        float q = quantv(ab[j], sf);
        #pragma unroll
        for (int c = 0; c < 10; ++c) acc[c] = fmaf(q, wdi[c * 2048 + j], acc[c]);
    }
    #pragma unroll
    for (int c = 0; c < 10; ++c)
        #pragma unroll
        for (int o = 32; o; o >>= 1) acc[c] += __shfl_down(acc[c], o, 64);
    __shared__ float red[4][10];
    int wid = threadIdx.x >> 6;
    if ((threadIdx.x & 63) == 0)
        #pragma unroll
        for (int c = 0; c < 10; ++c) red[wid][c] = acc[c];
    __syncthreads();
    if (threadIdx.x < 10) {
        int c = threadIdx.x;
        float s = red[0][c] + red[1][c] + red[2][c] + red[3][c];
        float bsf = wsfd[c] * sf;
        float bint = rintf(bd[c] / bsf);
        logits[b * 10 + c] = (s + bint) * bsf;
    }
}

// ---------------- softmax over batch axis (dim 0) ----------------
__global__ __launch_bounds__(256) void k_softmax(const float* __restrict__ logits, float* __restrict__ out) {
    int c = blockIdx.x;
    float v[4];
    #pragma unroll
    for (int k = 0; k < 4; ++k) v[k] = logits[(threadIdx.x + 256 * k) * 10 + c];
    float mx = fmaxf(fmaxf(v[0], v[1]), fmaxf(v[2], v[3]));
    __shared__ float redm[4];
    __shared__ float reds[4];
    #pragma unroll
    for (int o = 32; o; o >>= 1) mx = fmaxf(mx, __shfl_down(mx, o, 64));
    if ((threadIdx.x & 63) == 0) redm[threadIdx.x >> 6] = mx;
    __syncthreads();
    mx = fmaxf(fmaxf(redm[0], redm[1]), fmaxf(redm[2], redm[3]));
    float e[4], s = 0.f;
    #pragma unroll
    for (int k = 0; k < 4; ++k) { e[k] = expf(v[k] - mx); s += e[k]; }
    #pragma unroll
    for (int o = 32; o; o >>= 1) s += __shfl_down(s, o, 64);
    if ((threadIdx.x & 63) == 0) reds[threadIdx.x >> 6] = s;
    __syncthreads();
    s = reds[0] + reds[1] + reds[2] + reds[3];
    #pragma unroll
    for (int k = 0; k < 4; ++k) out[(threadIdx.x + 256 * k) * 10 + c] = e[k] / s;
}

extern "C" void kernel_launch(void* const* d_in, const int* in_sizes, int n_in,
                              void* d_out, int out_size, void* d_ws, size_t ws_size,
                              hipStream_t stream) {
    (void)in_sizes; (void)n_in; (void)out_size; (void)ws_size;
    const float* x = (const float*)d_in[0];
    const float *w[5], *bia[5], *g[5], *bb[5], *m[5], *v[5];
    for (int i = 0; i < 5; ++i) {
        w[i]   = (const float*)d_in[1 + 6 * i + 0];
        bia[i] = (const float*)d_in[1 + 6 * i + 1];
        g[i]   = (const float*)d_in[1 + 6 * i + 2];
        bb[i]  = (const float*)d_in[1 + 6 * i + 3];
        m[i]   = (const float*)d_in[1 + 6 * i + 4];
        v[i]   = (const float*)d_in[1 + 6 * i + 5];
    }
    const float* wd = (const float*)d_in[31];
    const float* bd = (const float*)d_in[32];
    float* ws = (float*)d_ws;
    unsigned* umax = (unsigned*)ws;
    float* out = (float*)d_out;

    float* wsf0 = ws + OFF_WSF0; float* bns0 = ws + OFF_BNS0; float* bnb0 = ws + OFF_BNB0; float* w0i = ws + OFF_W0I;
    float* wsf1 = ws + OFF_WSF1; float* bns1 = ws + OFF_BNS1; float* bnb1 = ws + OFF_BNB1; float* w1i = ws + OFF_W1I;
    float* wsf2 = ws + OFF_WSF2; float* bns2 = ws + OFF_BNS2; float* bnb2 = ws + OFF_BNB2; float* w2i = ws + OFF_W2I;
    float* wsf3 = ws + OFF_WSF3; float* bns3 = ws + OFF_BNS3; float* bnb3 = ws + OFF_BNB3; float* w3i = ws + OFF_W3I;
    float* wsf4 = ws + OFF_WSF4; float* bns4 = ws + OFF_BNS4; float* bnb4 = ws + OFF_BNB4; float* w4i = ws + OFF_W4I;
    float* wsfd = ws + OFF_WSFD; float* wdi = ws + OFF_WDI;
    float* logits = ws + OFF_LOG;
    float* actA = ws + ACT_A_OFF;   // act2 / act4
    float* actB = ws + ACT_B_OFF;   // act1 / act3

    PrepAll pa;
    pa.umax = umax;
    const float* ww[6] = {w[0], w[1], w[2], w[3], w[4], wd};
    float* wsfp[6] = {wsf0, wsf1, wsf2, wsf3, wsf4, wsfd};
    float* wip[6]  = {w0i, w1i, w2i, w3i, w4i, wdi};
    float* bnsp[6] = {bns0, bns1, bns2, bns3, bns4, nullptr};
    float* bnbp[6] = {bnb0, bnb1, bnb2, bnb3, bnb4, nullptr};
    int Ks[6] = {27, 32, 36, 288, 288, 2048};
    for (int i = 0; i < 6; ++i) {
        pa.e[i].w = ww[i];
        pa.e[i].g = (i < 5) ? g[i] : nullptr;
        pa.e[i].bb = (i < 5) ? bb[i] : nullptr;
        pa.e[i].m = (i < 5) ? m[i] : nullptr;
        pa.e[i].v = (i < 5) ? v[i] : nullptr;
        pa.e[i].wsf = wsfp[i];
        pa.e[i].wint = wip[i];
        pa.e[i].bns = bnsp[i];
        pa.e[i].bnb = bnbp[i];
        pa.e[i].K = Ks[i];
        pa.e[i].has_bn = (i < 5) ? 1 : 0;
    }

    hipLaunchKernelGGL(k_prep_all, dim3(143), dim3(256), 0, stream, pa);
    hipLaunchKernelGGL(k_absmax, dim3(256), dim3(256), 0, stream,
                       (const float4*)x, 1024 * 3 * 32 * 32 / 4, umax + 0);
    hipLaunchKernelGGL(k_conv0maxN, dim3(4096), dim3(256), 0, stream,
                       x, w0i, wsf0, bia[0], bns0, bnb0, umax, umax + 1);
    hipLaunchKernelGGL(k_conv01n, dim3(4096), dim3(256), 0, stream,
                       x, w0i, wsf0, bia[0], bns0, bnb0,
                       w1i, wsf1, bia[1], bns1, bnb1, umax, umax + 2, actB);
    hipLaunchKernelGGL(k_conv2c, dim3(1024), dim3(256), 0, stream,
                       actB, w2i, wsf2, bia[2], bns2, bnb2, umax, umax + 3, actA);
    hipLaunchKernelGGL((k_conv34b<16, 2>), dim3(512), dim3(256), 0, stream,
                       actA, w3i, wsf3, bia[3], bns3, bnb3, umax, 3, umax + 4, actB);
    hipLaunchKernelGGL((k_conv34b<8, 1>),  dim3(512), dim3(256), 0, stream,
                       actB, w4i, wsf4, bia[4], bns4, bnb4, umax, 4, umax + 5, actA);
    hipLaunchKernelGGL(k_fc, dim3(1024), dim3(256), 0, stream, actA, wdi, wsfd, bd, umax, logits);
    hipLaunchKernelGGL(k_softmax, dim3(10), dim3(256), 0, stream, logits, out);
}